// Round 9
// baseline (140.463 us; speedup 1.0000x reference)
//
#include <hip/hip_runtime.h>
#include <stdint.h>
#include <stddef.h>

#define DEVI __device__ __forceinline__

typedef __bf16 bf16x8 __attribute__((ext_vector_type(8)));
typedef float  f32x4  __attribute__((ext_vector_type(4)));
typedef float  f32x16 __attribute__((ext_vector_type(16)));
typedef unsigned short u16;
typedef uint32_t u32;
typedef u16 u16x8 __attribute__((ext_vector_type(8)));
typedef u16 u16x4 __attribute__((ext_vector_type(4)));
typedef u32 u32x2 __attribute__((ext_vector_type(2)));
typedef u32 u32x4 __attribute__((ext_vector_type(4)));

typedef __attribute__((address_space(1))) void as1_void;
typedef __attribute__((address_space(3))) void as3_void;

static constexpr float SC = 0.18033688011112042f;  // (1/8) * log2(e)

DEVI u16 f2bf(float f) {
  uint32_t u = __builtin_bit_cast(uint32_t, f);
  u += 0x7fffu + ((u >> 16) & 1u);
  return (u16)(u >> 16);
}

DEVI void gload_lds16(const void* g, void* l) {
  __builtin_amdgcn_global_load_lds((as1_void*)(void*)g, (as3_void*)l, 16, 0, 0);
}

#if __has_builtin(__builtin_amdgcn_exp2f)
DEVI float fast_exp2(float x) { return __builtin_amdgcn_exp2f(x); }
#else
DEVI float fast_exp2(float x) { return exp2f(x); }
#endif

DEVI u32 cvtpk(float lo, float hi) {
  u32 r;
  asm("v_cvt_pk_bf16_f32 %0, %1, %2" : "=v"(r) : "v"(lo), "v"(hi));
  return r;
}
DEVI void plswap(u32& a, u32& b) {
  asm("v_permlane32_swap_b32 %0, %1" : "+v"(a), "+v"(b));
}

// ---------------- elementwise fp32 -> bf16 ----------------
__global__ __launch_bounds__(256) void k_cvt(const float* __restrict__ in,
                                             u16* __restrict__ out, int n) {
  int i = (blockIdx.x * 256 + threadIdx.x) * 4;
  if (i >= n) return;
  const float4 v = *(const float4*)(in + i);
  u16x4 o = { f2bf(v.x), f2bf(v.y), f2bf(v.z), f2bf(v.w) };
  *(u16x4*)(out + i) = o;
}

// ------------- transpose + convert: in fp32 [R][C] -> out bf16 [C][R] -------------
__global__ __launch_bounds__(256) void k_tcvt(const float* __restrict__ in,
                                              u16* __restrict__ out, int R, int C) {
  __shared__ float tile[32][33];
  const int c0 = blockIdx.x * 32, r0 = blockIdx.y * 32;
  const int tx = threadIdx.x, ty = threadIdx.y;
#pragma unroll
  for (int i = ty; i < 32; i += 8)
    tile[i][tx] = in[(size_t)(r0 + i) * C + (c0 + tx)];
  __syncthreads();
#pragma unroll
  for (int i = ty; i < 32; i += 8)
    out[(size_t)(c0 + i) * R + (r0 + tx)] = f2bf(tile[tx][i]);
}

// ------------- per-head bf16 transpose: [S 2048][d 64] -> [d 64][S 2048] -------------
// grid (S/64, BH=32), 256 thr; 64x64 LDS tile, coalesced u16x8 on both sides.
__global__ __launch_bounds__(256) void k_vt(const u16* __restrict__ in,
                                            u16* __restrict__ out) {
  __shared__ u16 tile[64][72];
  const int tid = threadIdx.x;
  const int s0 = blockIdx.x * 64;
  const int bh = blockIdx.y;
  const size_t ib = (size_t)bh * 131072;
#pragma unroll
  for (int it = 0; it < 2; ++it) {
    const int r = (tid >> 3) + it * 32;
    const int c8 = (tid & 7) * 8;
    u16x8 v = *(const u16x8*)(in + ib + (size_t)(s0 + r) * 64 + c8);
    *(u16x8*)&tile[r][c8] = v;
  }
  __syncthreads();
#pragma unroll
  for (int it = 0; it < 2; ++it) {
    const int d = (tid >> 3) + it * 32;
    const int s8 = (tid & 7) * 8;
    u16x8 v;
#pragma unroll
    for (int jj = 0; jj < 8; ++jj) v[jj] = tile[s8 + jj][d];
    *(u16x8*)(out + ib + (size_t)d * 2048 + s0 + s8) = v;
  }
}

// ---------------- GEMM: C[M][N] = A[M][K] * Bt[N][K]^T  (bf16 in, fp32 acc) ----------------
// 2-phase double-buffered staging (STAGE next tile before computing current).
// EPI 0: qkv epilogue -> q,k,v bf16 [B,H,S,d] (all coalesced) + present fp32
// EPI 1: proj epilogue (fp32 out + bias)
template <int EPI>
__global__ __launch_bounds__(256) void k_gemm(
    const u16* __restrict__ A, const u16* __restrict__ Bt,
    const float* __restrict__ bias,
    u16* __restrict__ wq, u16* __restrict__ wk, u16* __restrict__ wv,
    float* __restrict__ pk, float* __restrict__ pv, float* __restrict__ of) {
  constexpr int K = 1024;
  __shared__ __align__(16) u16 Ash[2][128 * 32];
  __shared__ __align__(16) u16 Bsh[2][128 * 32];
  const int tid = threadIdx.x;
  const int lane = tid & 63, wid = tid >> 6;
  const int wm = wid >> 1, wn = wid & 1;
  const int lr = lane & 15, lg = lane >> 4;
  const int m0 = blockIdx.y * 128, n0 = blockIdx.x * 128;

  const int c = wid * 64 + lane;  // 16B chunk id, 0..255
  const u16* Ag1 = A + (size_t)(m0 + (c >> 2)) * K + (c & 3) * 8;
  const u16* Ag2 = A + (size_t)(m0 + 64 + (c >> 2)) * K + (c & 3) * 8;
  const u16* Bg1 = Bt + (size_t)(n0 + (c >> 2)) * K + (c & 3) * 8;
  const u16* Bg2 = Bt + (size_t)(n0 + 64 + (c >> 2)) * K + (c & 3) * 8;

  f32x4 acc[4][4];
#pragma unroll
  for (int i = 0; i < 4; ++i)
#pragma unroll
    for (int j = 0; j < 4; ++j) acc[i][j] = (f32x4)0.0f;

#define STAGE(sel, kk)                                        \
  {                                                           \
    gload_lds16(Ag1 + (kk), &Ash[sel][wid * 512]);            \
    gload_lds16(Ag2 + (kk), &Ash[sel][2048 + wid * 512]);     \
    gload_lds16(Bg1 + (kk), &Bsh[sel][wid * 512]);            \
    gload_lds16(Bg2 + (kk), &Bsh[sel][2048 + wid * 512]);     \
  }

  STAGE(0, 0)
  __syncthreads();
  int cur = 0;
  for (int k0 = 0; k0 < K; k0 += 32) {
    if (k0 + 32 < K) STAGE(cur ^ 1, k0 + 32)
    bf16x8 af[4], bfr[4];
#pragma unroll
    for (int f = 0; f < 4; ++f) {
      af[f]  = *(const bf16x8*)&Ash[cur][(wm * 64 + f * 16 + lr) * 32 + lg * 8];
      bfr[f] = *(const bf16x8*)&Bsh[cur][(wn * 64 + f * 16 + lr) * 32 + lg * 8];
    }
#pragma unroll
    for (int i = 0; i < 4; ++i)
#pragma unroll
      for (int j = 0; j < 4; ++j)
        acc[i][j] = __builtin_amdgcn_mfma_f32_16x16x32_bf16(af[i], bfr[j], acc[i][j], 0, 0, 0);
    __syncthreads();  // drains next-tile loads (vmcnt0) + protects buffer reuse
    cur ^= 1;
  }
#undef STAGE

  if constexpr (EPI == 0) {
#pragma unroll
    for (int j = 0; j < 4; ++j) {
      const int n = n0 + wn * 64 + j * 16 + lr;
      const float bv = bias[n];
      const int sec = n >> 10;
      const int nn = n & 1023;
      const int h = nn >> 6, dd = nn & 63;
#pragma unroll
      for (int i = 0; i < 4; ++i) {
        const int mb = m0 + wm * 64 + i * 16 + lg * 4;
        const int bb = mb >> 11, ss = mb & 2047;
        const size_t ib = (size_t)(bb * 16 + h) * 131072 + (size_t)ss * 64 + dd;
        if (sec == 0) {
#pragma unroll
          for (int r = 0; r < 4; ++r)
            wq[ib + (size_t)r * 64] = f2bf(acc[i][j][r] + bv);
        } else if (sec == 1) {
#pragma unroll
          for (int r = 0; r < 4; ++r) {
            const float v = acc[i][j][r] + bv;
            wk[ib + (size_t)r * 64] = f2bf(v);
            pk[ib + (size_t)r * 64] = v;
          }
        } else {
#pragma unroll
          for (int r = 0; r < 4; ++r) {
            const float v = acc[i][j][r] + bv;
            wv[ib + (size_t)r * 64] = f2bf(v);
            pv[ib + (size_t)r * 64] = v;
          }
        }
      }
    }
  } else {
#pragma unroll
    for (int j = 0; j < 4; ++j) {
      const int n = n0 + wn * 64 + j * 16 + lr;
      const float bv = bias[n];
#pragma unroll
      for (int i = 0; i < 4; ++i) {
        const int mb = m0 + wm * 64 + i * 16 + lg * 4;
#pragma unroll
        for (int r = 0; r < 4; ++r)
          of[(size_t)(mb + r) * 1024 + n] = acc[i][j][r] + bv;
      }
    }
  }
}

// ---------------- causal flash attention: tri-buffered LDS K/V, counted vmcnt ----------------
// 1024 blocks x 128 thr (2 waves). bh = bid&31 (XCD-pinned).
// Balanced 4-class qt mapping: with bid%256 ~ CU, each CU's 4 blocks have
// T = {32-g, g+1, 24-g, 9+g} summing to 66 KV-iters exactly; longest class first.
// Triple-buffered LDS + counted s_waitcnt vmcnt(8) + raw s_barrier: loads for
// tile j+2 stay in flight across the barrier (T3/T4) instead of the
// __syncthreads vmcnt(0) drain that nullified the dbuf prefetch.
__global__ __launch_bounds__(128) void k_attn(const u16* __restrict__ Q,
                                              const u16* __restrict__ Kp,
                                              const u16* __restrict__ VT,
                                              u16* __restrict__ AO) {
  __shared__ __align__(16) u16 Ksh[3][4096];  // [kpos 64][d 64], swizzled
  __shared__ __align__(16) u16 Vsh[3][4096];  // [d 64][kpos 64], swizzled

  const int tid = threadIdx.x;
  const int lane = tid & 63, w = tid >> 6;    // w in {0,1}
  const int l31 = lane & 31, hi = lane >> 5;
  const int bid = blockIdx.x;
  const int bh = bid & 31;                    // bh%8 == bid%8 -> XCD-pinned
  const int j4 = bid >> 8;                    // work class 0..3
  const int g  = (bid >> 5) & 7;
  const int qt = (j4 == 0) ? (31 - g) : (j4 == 1) ? g : (j4 == 2) ? (23 - g) : (8 + g);
  const int b = bh >> 4, h = bh & 15;
  const size_t hb = (size_t)bh * (2048 * 64);

  const int T = qt + 1;                       // KV tiles (diag = T-1 for both waves)
  const int qb = qt * 64 + w * 32;            // this wave's 32 q-rows

  // staging source (pre-swizzled): (row & 7) == (lane>>3) regardless of chunk
  const int srow = w * 32 + (lane >> 3);
  const int sslot = (lane & 7) ^ (lane >> 3);
  const u16* Kg = Kp + hb + (size_t)srow * 64 + sslot * 8;
  const u16* Vg = VT + hb + (size_t)srow * 2048 + sslot * 8;

#define STAGEA(sel, jt)                                                       \
  {                                                                           \
    gload_lds16(Kg + (size_t)(jt) * 4096,          &Ksh[sel][w * 2048]);      \
    gload_lds16(Kg + (size_t)(jt) * 4096 + 512,    &Ksh[sel][w * 2048 + 512]);\
    gload_lds16(Kg + (size_t)(jt) * 4096 + 1024,   &Ksh[sel][w * 2048 + 1024]);\
    gload_lds16(Kg + (size_t)(jt) * 4096 + 1536,   &Ksh[sel][w * 2048 + 1536]);\
    gload_lds16(Vg + (size_t)(jt) * 64,            &Vsh[sel][w * 2048]);      \
    gload_lds16(Vg + (size_t)(jt) * 64 + 16384,    &Vsh[sel][w * 2048 + 512]);\
    gload_lds16(Vg + (size_t)(jt) * 64 + 32768,    &Vsh[sel][w * 2048 + 1024]);\
    gload_lds16(Vg + (size_t)(jt) * 64 + 49152,    &Vsh[sel][w * 2048 + 1536]);\
  }

  // Q fragments (held in registers for the whole block)
  const u16* Qp = Q + hb + (size_t)(qb + l31) * 64 + hi * 8;
  const bf16x8 qf0 = *(const bf16x8*)(Qp);
  const bf16x8 qf1 = *(const bf16x8*)(Qp + 16);
  const bf16x8 qf2 = *(const bf16x8*)(Qp + 32);
  const bf16x8 qf3 = *(const bf16x8*)(Qp + 48);

  f32x16 o0 = (f32x16)0.0f, o1 = (f32x16)0.0f;
  float mrun = -1e30f, lrun = 0.0f;

  const int xr = l31 & 7;  // read-side swizzle key

  STAGEA(0, 0)
  if (T > 1) {
    STAGEA(1, 1)
    asm volatile("s_waitcnt vmcnt(8)" ::: "memory");
  } else {
    asm volatile("s_waitcnt vmcnt(0)" ::: "memory");
  }
  __builtin_amdgcn_sched_barrier(0);
  __builtin_amdgcn_s_barrier();
  __builtin_amdgcn_sched_barrier(0);

  int cur = 0;
  for (int jt = 0; jt < T; ++jt) {
    const bool pf = (jt + 2 < T);
    int nb = cur + 2; if (nb >= 3) nb -= 3;
    if (pf) STAGEA(nb, jt + 2)
    const u16* Kb = Ksh[cur];
    const u16* Vb = Vsh[cur];
    // K fragments: row = s*32+l31, want slot 2c+hi -> read slot ^ (row&7)
    bf16x8 kf[2][4];
#pragma unroll
    for (int s = 0; s < 2; ++s)
#pragma unroll
      for (int c = 0; c < 4; ++c)
        kf[s][c] = *(const bf16x8*)&Kb[(s * 32 + l31) * 64 + (((2 * c + hi) ^ xr) * 8)];

    // S^T[kpos][q] = K . Q^T
    f32x16 s0 = (f32x16)0.0f, s1 = (f32x16)0.0f;
    __builtin_amdgcn_s_setprio(1);
    s0 = __builtin_amdgcn_mfma_f32_32x32x16_bf16(kf[0][0], qf0, s0, 0, 0, 0);
    s1 = __builtin_amdgcn_mfma_f32_32x32x16_bf16(kf[1][0], qf0, s1, 0, 0, 0);
    s0 = __builtin_amdgcn_mfma_f32_32x32x16_bf16(kf[0][1], qf1, s0, 0, 0, 0);
    s1 = __builtin_amdgcn_mfma_f32_32x32x16_bf16(kf[1][1], qf1, s1, 0, 0, 0);
    s0 = __builtin_amdgcn_mfma_f32_32x32x16_bf16(kf[0][2], qf2, s0, 0, 0, 0);
    s1 = __builtin_amdgcn_mfma_f32_32x32x16_bf16(kf[1][2], qf2, s1, 0, 0, 0);
    s0 = __builtin_amdgcn_mfma_f32_32x32x16_bf16(kf[0][3], qf3, s0, 0, 0, 0);
    s1 = __builtin_amdgcn_mfma_f32_32x32x16_bf16(kf[1][3], qf3, s1, 0, 0, 0);
    __builtin_amdgcn_s_setprio(0);

    // causal mask (diagonal tile only; qrel = w*32 + l31)
    if (jt == T - 1) {
      const int qrel = w * 32 + l31;
      const int h4 = hi * 4;
#pragma unroll
      for (int r = 0; r < 16; ++r) {
        const int kp = (r & 3) + ((r >> 2) << 3) + h4;
        s0[r] = (kp <= qrel) ? s0[r] : -1e30f;
        s1[r] = (kp + 32 <= qrel) ? s1[r] : -1e30f;
      }
    }

    // ---- in-register online softmax (lane pair (l31,hi) = one q-row) ----
    float t8[8];
#pragma unroll
    for (int r = 0; r < 8; ++r)
      t8[r] = fmaxf(fmaxf(s0[r], s0[r + 8]), fmaxf(s1[r], s1[r + 8]));
    float tm = fmaxf(fmaxf(fmaxf(t8[0], t8[1]), fmaxf(t8[2], t8[3])),
                     fmaxf(fmaxf(t8[4], t8[5]), fmaxf(t8[6], t8[7])));
    tm = fmaxf(tm, __shfl_xor(tm, 32));
    if (!__all(tm <= mrun)) {
      const float mnew = fmaxf(mrun, tm);
      const float al = fast_exp2((mrun - mnew) * SC);
      mrun = mnew;
      lrun *= al;
#pragma unroll
      for (int r = 0; r < 16; ++r) { o0[r] *= al; o1[r] *= al; }
    }
    const float nb2 = -mrun * SC;
#pragma unroll
    for (int r = 0; r < 16; ++r) {
      s0[r] = fast_exp2(fmaf(s0[r], SC, nb2));
      s1[r] = fast_exp2(fmaf(s1[r], SC, nb2));
    }
    float u8[8];
#pragma unroll
    for (int r = 0; r < 8; ++r)
      u8[r] = (s0[r] + s0[r + 8]) + (s1[r] + s1[r + 8]);
    lrun += ((u8[0] + u8[1]) + (u8[2] + u8[3])) + ((u8[4] + u8[5]) + (u8[6] + u8[7]));

    // ---- pack P to bf16 B-fragments (cvt_pk + permlane32_swap, T12) ----
    bf16x8 pb0, pb1, pb2, pb3;
#define PACK_CHUNK(sv, bb, dst)                                   \
    {                                                             \
      u32 a0 = cvtpk(sv[bb + 0], sv[bb + 1]);                     \
      u32 a1 = cvtpk(sv[bb + 2], sv[bb + 3]);                     \
      u32 a2 = cvtpk(sv[bb + 4], sv[bb + 5]);                     \
      u32 a3 = cvtpk(sv[bb + 6], sv[bb + 7]);                     \
      plswap(a0, a2);                                             \
      plswap(a1, a3);                                             \
      u32x4 fv = {a0, a1, a2, a3};                                \
      dst = __builtin_bit_cast(bf16x8, fv);                       \
    }
    PACK_CHUNK(s0, 0, pb0)
    PACK_CHUNK(s0, 8, pb1)
    PACK_CHUNK(s1, 0, pb2)
    PACK_CHUNK(s1, 8, pb3)
#undef PACK_CHUNK

    // V^T fragments: row = mt*32+l31 (d), want slot 2c+hi -> read slot ^ (row&7)
    bf16x8 vf[2][4];
#pragma unroll
    for (int mt = 0; mt < 2; ++mt)
#pragma unroll
      for (int c = 0; c < 4; ++c)
        vf[mt][c] = *(const bf16x8*)&Vb[(mt * 32 + l31) * 64 + (((2 * c + hi) ^ xr) * 8)];

    // ---- O^T[d][q] += V^T . P^T ----
    __builtin_amdgcn_s_setprio(1);
    o0 = __builtin_amdgcn_mfma_f32_32x32x16_bf16(vf[0][0], pb0, o0, 0, 0, 0);
    o1 = __builtin_amdgcn_mfma_f32_32x32x16_bf16(vf[1][0], pb0, o1, 0, 0, 0);
    o0 = __builtin_amdgcn_mfma_f32_32x32x16_bf16(vf[0][1], pb1, o0, 0, 0, 0);
    o1 = __builtin_amdgcn_mfma_f32_32x32x16_bf16(vf[1][1], pb1, o1, 0, 0, 0);
    o0 = __builtin_amdgcn_mfma_f32_32x32x16_bf16(vf[0][2], pb2, o0, 0, 0, 0);
    o1 = __builtin_amdgcn_mfma_f32_32x32x16_bf16(vf[1][2], pb2, o1, 0, 0, 0);
    o0 = __builtin_amdgcn_mfma_f32_32x32x16_bf16(vf[0][3], pb3, o0, 0, 0, 0);
    o1 = __builtin_amdgcn_mfma_f32_32x32x16_bf16(vf[1][3], pb3, o1, 0, 0, 0);
    __builtin_amdgcn_s_setprio(0);

    // counted wait: keep the 8 loads for tile jt+2 in flight across the barrier
    if (pf) asm volatile("s_waitcnt vmcnt(8)" ::: "memory");
    else    asm volatile("s_waitcnt vmcnt(0)" ::: "memory");
    __builtin_amdgcn_sched_barrier(0);
    __builtin_amdgcn_s_barrier();
    __builtin_amdgcn_sched_barrier(0);
    cur = (cur + 1 == 3) ? 0 : cur + 1;
  }
#undef STAGEA

  // ---- epilogue: combine partner row-sums, normalize, store bf16 (per wave) ----
  const float lt = lrun + __shfl_xor(lrun, 32);
  const float inv = 1.0f / lt;
  u16* aorow = AO + (size_t)(b * 2048 + qb + l31) * 1024 + h * 64 + hi * 4;
#pragma unroll
  for (int g2 = 0; g2 < 4; ++g2) {
    u32 w0 = cvtpk(o0[4 * g2 + 0] * inv, o0[4 * g2 + 1] * inv);
    u32 w1 = cvtpk(o0[4 * g2 + 2] * inv, o0[4 * g2 + 3] * inv);
    u32x2 ww = {w0, w1};
    *(u32x2*)(aorow + g2 * 8) = ww;
  }
#pragma unroll
  for (int g2 = 0; g2 < 4; ++g2) {
    u32 w0 = cvtpk(o1[4 * g2 + 0] * inv, o1[4 * g2 + 1] * inv);
    u32 w1 = cvtpk(o1[4 * g2 + 2] * inv, o1[4 * g2 + 3] * inv);
    u32x2 ww = {w0, w1};
    *(u32x2*)(aorow + 32 + g2 * 8) = ww;
  }
}

extern "C" void kernel_launch(void* const* d_in, const int* in_sizes, int n_in,
                              void* d_out, int out_size, void* d_ws, size_t ws_size,
                              hipStream_t stream) {
  const float* x      = (const float*)d_in[0];
  const float* w_attn = (const float*)d_in[1];
  const float* b_attn = (const float*)d_in[2];
  const float* w_proj = (const float*)d_in[3];
  const float* b_proj = (const float*)d_in[4];
  float* out = (float*)d_out;

  char* ws = (char*)d_ws;
  u16* x_bf  = (u16*)(ws);                    // [4096][1024] bf16 (8 MB); dead after gemm0
  u16* wat_t = (u16*)(ws + 8388608);          // [3072][1024] bf16   (6 MB)
  u16* wpj_t = (u16*)(ws + 14680064);         // [1024][1024] bf16   (2 MB)
  u16* q_ws  = (u16*)(ws + 16777216);         // [B,H,S,d] bf16      (8 MB)
  u16* k_ws  = (u16*)(ws + 25165824);         // [B,H,S,d] bf16      (8 MB)
  u16* v_ws  = (u16*)(ws + 33554432);         // [B,H,S,d] bf16      (8 MB)
  u16* a_ws  = (u16*)(ws + 41943040);         // [B,S,nx]  bf16      (8 MB)
  u16* vT_ws = (u16*)(ws);                    // [B,H,d,S] bf16, reuses x_bf region

  k_cvt<<<4096, 256, 0, stream>>>(x, x_bf, 4194304);
  k_tcvt<<<dim3(96, 32), dim3(32, 8), 0, stream>>>(w_attn, wat_t, 1024, 3072);
  k_tcvt<<<dim3(32, 32), dim3(32, 8), 0, stream>>>(w_proj, wpj_t, 1024, 1024);

  k_gemm<0><<<dim3(24, 32), 256, 0, stream>>>(x_bf, wat_t, b_attn,
                                              q_ws, k_ws, v_ws,
                                              out + 4194304, out + 8388608, nullptr);

  k_vt<<<dim3(32, 32), 256, 0, stream>>>(v_ws, vT_ws);

  k_attn<<<dim3(1024), 128, 0, stream>>>(q_ws, k_ws, vT_ws, a_ws);

  k_gemm<1><<<dim3(8, 32), 256, 0, stream>>>(a_ws, wpj_t, b_proj,
                                             nullptr, nullptr, nullptr,
                                             nullptr, nullptr, out);
}

// Round 10
// 138.379 us; speedup vs baseline: 1.0151x; 1.0151x over previous
//
#include <hip/hip_runtime.h>
#include <stdint.h>
#include <stddef.h>

#define DEVI __device__ __forceinline__

typedef __bf16 bf16x8 __attribute__((ext_vector_type(8)));
typedef float  f32x4  __attribute__((ext_vector_type(4)));
typedef float  f32x16 __attribute__((ext_vector_type(16)));
typedef unsigned short u16;
typedef uint32_t u32;
typedef u16 u16x8 __attribute__((ext_vector_type(8)));
typedef u16 u16x4 __attribute__((ext_vector_type(4)));
typedef u32 u32x2 __attribute__((ext_vector_type(2)));
typedef u32 u32x4 __attribute__((ext_vector_type(4)));

typedef __attribute__((address_space(1))) void as1_void;
typedef __attribute__((address_space(3))) void as3_void;

static constexpr float SC = 0.18033688011112042f;  // (1/8) * log2(e)

DEVI u16 f2bf(float f) {
  uint32_t u = __builtin_bit_cast(uint32_t, f);
  u += 0x7fffu + ((u >> 16) & 1u);
  return (u16)(u >> 16);
}

DEVI void gload_lds16(const void* g, void* l) {
  __builtin_amdgcn_global_load_lds((as1_void*)(void*)g, (as3_void*)l, 16, 0, 0);
}

#if __has_builtin(__builtin_amdgcn_exp2f)
DEVI float fast_exp2(float x) { return __builtin_amdgcn_exp2f(x); }
#else
DEVI float fast_exp2(float x) { return exp2f(x); }
#endif

DEVI u32 cvtpk(float lo, float hi) {
  u32 r;
  asm("v_cvt_pk_bf16_f32 %0, %1, %2" : "=v"(r) : "v"(lo), "v"(hi));
  return r;
}
DEVI void plswap(u32& a, u32& b) {
  asm("v_permlane32_swap_b32 %0, %1" : "+v"(a), "+v"(b));
}

// ---------------- elementwise fp32 -> bf16 ----------------
__global__ __launch_bounds__(256) void k_cvt(const float* __restrict__ in,
                                             u16* __restrict__ out, int n) {
  int i = (blockIdx.x * 256 + threadIdx.x) * 4;
  if (i >= n) return;
  const float4 v = *(const float4*)(in + i);
  u16x4 o = { f2bf(v.x), f2bf(v.y), f2bf(v.z), f2bf(v.w) };
  *(u16x4*)(out + i) = o;
}

// ------------- transpose + convert: in fp32 [R][C] -> out bf16 [C][R] -------------
__global__ __launch_bounds__(256) void k_tcvt(const float* __restrict__ in,
                                              u16* __restrict__ out, int R, int C) {
  __shared__ float tile[32][33];
  const int c0 = blockIdx.x * 32, r0 = blockIdx.y * 32;
  const int tx = threadIdx.x, ty = threadIdx.y;
#pragma unroll
  for (int i = ty; i < 32; i += 8)
    tile[i][tx] = in[(size_t)(r0 + i) * C + (c0 + tx)];
  __syncthreads();
#pragma unroll
  for (int i = ty; i < 32; i += 8)
    out[(size_t)(c0 + i) * R + (r0 + tx)] = f2bf(tile[tx][i]);
}

// ------------- per-head bf16 transpose: [S 2048][d 64] -> [d 64][S 2048] -------------
__global__ __launch_bounds__(256) void k_vt(const u16* __restrict__ in,
                                            u16* __restrict__ out) {
  __shared__ u16 tile[64][72];
  const int tid = threadIdx.x;
  const int s0 = blockIdx.x * 64;
  const int bh = blockIdx.y;
  const size_t ib = (size_t)bh * 131072;
#pragma unroll
  for (int it = 0; it < 2; ++it) {
    const int r = (tid >> 3) + it * 32;
    const int c8 = (tid & 7) * 8;
    u16x8 v = *(const u16x8*)(in + ib + (size_t)(s0 + r) * 64 + c8);
    *(u16x8*)&tile[r][c8] = v;
  }
  __syncthreads();
#pragma unroll
  for (int it = 0; it < 2; ++it) {
    const int d = (tid >> 3) + it * 32;
    const int s8 = (tid & 7) * 8;
    u16x8 v;
#pragma unroll
    for (int jj = 0; jj < 8; ++jj) v[jj] = tile[s8 + jj][d];
    *(u16x8*)(out + ib + (size_t)d * 2048 + s0 + s8) = v;
  }
}

// ---------------- GEMM: C[M][N] = A[M][K] * Bt[N][K]^T  (bf16 in, fp32 acc) ----------------
// Tri-buffered LDS + counted s_waitcnt vmcnt(4) + raw s_barrier: tile j+2's loads
// stay in flight across the barrier (T3/T4) instead of the __syncthreads vmcnt(0)
// drain. T1 XCD-chunked bid remap for A-panel L2 locality.
// EPI 0: qkv epilogue -> q,k,v bf16 [B,H,S,d] (coalesced) + present fp32
// EPI 1: proj epilogue (fp32 out + bias)
template <int EPI>
__global__ __launch_bounds__(256) void k_gemm(
    const u16* __restrict__ A, const u16* __restrict__ Bt,
    const float* __restrict__ bias,
    u16* __restrict__ wq, u16* __restrict__ wk, u16* __restrict__ wv,
    float* __restrict__ pk, float* __restrict__ pv, float* __restrict__ of) {
  constexpr int K = 1024;
  constexpr int NT = K / 32;
  __shared__ __align__(16) u16 Ash[3][128 * 32];
  __shared__ __align__(16) u16 Bsh[3][128 * 32];
  const int tid = threadIdx.x;
  const int lane = tid & 63, wid = tid >> 6;
  const int wm = wid >> 1, wn = wid & 1;
  const int lr = lane & 15, lg = lane >> 4;

  // T1: XCD-chunked remap (nwg % 8 == 0 in both uses -> bijective)
  const int nwgx = gridDim.x;
  const int nwg = nwgx * gridDim.y;
  int lbid = blockIdx.y * nwgx + blockIdx.x;
  lbid = (lbid & 7) * (nwg >> 3) + (lbid >> 3);
  const int m0 = (lbid / nwgx) * 128, n0 = (lbid % nwgx) * 128;

  const int c = wid * 64 + lane;  // 16B chunk id, 0..255
  const u16* Ag1 = A + (size_t)(m0 + (c >> 2)) * K + (c & 3) * 8;
  const u16* Ag2 = A + (size_t)(m0 + 64 + (c >> 2)) * K + (c & 3) * 8;
  const u16* Bg1 = Bt + (size_t)(n0 + (c >> 2)) * K + (c & 3) * 8;
  const u16* Bg2 = Bt + (size_t)(n0 + 64 + (c >> 2)) * K + (c & 3) * 8;

  f32x4 acc[4][4];
#pragma unroll
  for (int i = 0; i < 4; ++i)
#pragma unroll
    for (int j = 0; j < 4; ++j) acc[i][j] = (f32x4)0.0f;

#define STAGE(sel, kk)                                        \
  {                                                           \
    gload_lds16(Ag1 + (kk), &Ash[sel][wid * 512]);            \
    gload_lds16(Ag2 + (kk), &Ash[sel][2048 + wid * 512]);     \
    gload_lds16(Bg1 + (kk), &Bsh[sel][wid * 512]);            \
    gload_lds16(Bg2 + (kk), &Bsh[sel][2048 + wid * 512]);     \
  }

  STAGE(0, 0)
  STAGE(1, 32)
  asm volatile("s_waitcnt vmcnt(4)" ::: "memory");
  __builtin_amdgcn_sched_barrier(0);
  __builtin_amdgcn_s_barrier();
  __builtin_amdgcn_sched_barrier(0);

  int cur = 0;
  for (int j = 0; j < NT; ++j) {
    const bool pf = (j + 2 < NT);
    int nb = cur + 2; if (nb >= 3) nb -= 3;
    if (pf) STAGE(nb, (j + 2) * 32)
    bf16x8 af[4], bfr[4];
#pragma unroll
    for (int f = 0; f < 4; ++f) {
      af[f]  = *(const bf16x8*)&Ash[cur][(wm * 64 + f * 16 + lr) * 32 + lg * 8];
      bfr[f] = *(const bf16x8*)&Bsh[cur][(wn * 64 + f * 16 + lr) * 32 + lg * 8];
    }
    __builtin_amdgcn_s_setprio(1);
#pragma unroll
    for (int i = 0; i < 4; ++i)
#pragma unroll
      for (int jj = 0; jj < 4; ++jj)
        acc[i][jj] = __builtin_amdgcn_mfma_f32_16x16x32_bf16(af[i], bfr[jj], acc[i][jj], 0, 0, 0);
    __builtin_amdgcn_s_setprio(0);
    // counted wait: keep tile j+2's 4 loads in flight across the barrier
    if (pf) asm volatile("s_waitcnt vmcnt(4)" ::: "memory");
    else    asm volatile("s_waitcnt vmcnt(0)" ::: "memory");
    __builtin_amdgcn_sched_barrier(0);
    __builtin_amdgcn_s_barrier();
    __builtin_amdgcn_sched_barrier(0);
    cur = (cur + 1 == 3) ? 0 : cur + 1;
  }
#undef STAGE

  if constexpr (EPI == 0) {
#pragma unroll
    for (int j = 0; j < 4; ++j) {
      const int n = n0 + wn * 64 + j * 16 + lr;
      const float bv = bias[n];
      const int sec = n >> 10;
      const int nn = n & 1023;
      const int h = nn >> 6, dd = nn & 63;
#pragma unroll
      for (int i = 0; i < 4; ++i) {
        const int mb = m0 + wm * 64 + i * 16 + lg * 4;
        const int bb = mb >> 11, ss = mb & 2047;
        const size_t ib = (size_t)(bb * 16 + h) * 131072 + (size_t)ss * 64 + dd;
        if (sec == 0) {
#pragma unroll
          for (int r = 0; r < 4; ++r)
            wq[ib + (size_t)r * 64] = f2bf(acc[i][j][r] + bv);
        } else if (sec == 1) {
#pragma unroll
          for (int r = 0; r < 4; ++r) {
            const float v = acc[i][j][r] + bv;
            wk[ib + (size_t)r * 64] = f2bf(v);
            pk[ib + (size_t)r * 64] = v;
          }
        } else {
#pragma unroll
          for (int r = 0; r < 4; ++r) {
            const float v = acc[i][j][r] + bv;
            wv[ib + (size_t)r * 64] = f2bf(v);
            pv[ib + (size_t)r * 64] = v;
          }
        }
      }
    }
  } else {
#pragma unroll
    for (int j = 0; j < 4; ++j) {
      const int n = n0 + wn * 64 + j * 16 + lr;
      const float bv = bias[n];
#pragma unroll
      for (int i = 0; i < 4; ++i) {
        const int mb = m0 + wm * 64 + i * 16 + lg * 4;
#pragma unroll
        for (int r = 0; r < 4; ++r)
          of[(size_t)(mb + r) * 1024 + n] = acc[i][j][r] + bv;
      }
    }
  }
}

// ---------------- causal flash attention: tri-buffered LDS K/V, counted vmcnt ----------------
// (unchanged from round 9)
__global__ __launch_bounds__(128) void k_attn(const u16* __restrict__ Q,
                                              const u16* __restrict__ Kp,
                                              const u16* __restrict__ VT,
                                              u16* __restrict__ AO) {
  __shared__ __align__(16) u16 Ksh[3][4096];  // [kpos 64][d 64], swizzled
  __shared__ __align__(16) u16 Vsh[3][4096];  // [d 64][kpos 64], swizzled

  const int tid = threadIdx.x;
  const int lane = tid & 63, w = tid >> 6;    // w in {0,1}
  const int l31 = lane & 31, hi = lane >> 5;
  const int bid = blockIdx.x;
  const int bh = bid & 31;                    // bh%8 == bid%8 -> XCD-pinned
  const int j4 = bid >> 8;                    // work class 0..3
  const int g  = (bid >> 5) & 7;
  const int qt = (j4 == 0) ? (31 - g) : (j4 == 1) ? g : (j4 == 2) ? (23 - g) : (8 + g);
  const int b = bh >> 4, h = bh & 15;
  const size_t hb = (size_t)bh * (2048 * 64);

  const int T = qt + 1;                       // KV tiles (diag = T-1 for both waves)
  const int qb = qt * 64 + w * 32;            // this wave's 32 q-rows

  // staging source (pre-swizzled): (row & 7) == (lane>>3) regardless of chunk
  const int srow = w * 32 + (lane >> 3);
  const int sslot = (lane & 7) ^ (lane >> 3);
  const u16* Kg = Kp + hb + (size_t)srow * 64 + sslot * 8;
  const u16* Vg = VT + hb + (size_t)srow * 2048 + sslot * 8;

#define STAGEA(sel, jt)                                                       \
  {                                                                           \
    gload_lds16(Kg + (size_t)(jt) * 4096,          &Ksh[sel][w * 2048]);      \
    gload_lds16(Kg + (size_t)(jt) * 4096 + 512,    &Ksh[sel][w * 2048 + 512]);\
    gload_lds16(Kg + (size_t)(jt) * 4096 + 1024,   &Ksh[sel][w * 2048 + 1024]);\
    gload_lds16(Kg + (size_t)(jt) * 4096 + 1536,   &Ksh[sel][w * 2048 + 1536]);\
    gload_lds16(Vg + (size_t)(jt) * 64,            &Vsh[sel][w * 2048]);      \
    gload_lds16(Vg + (size_t)(jt) * 64 + 16384,    &Vsh[sel][w * 2048 + 512]);\
    gload_lds16(Vg + (size_t)(jt) * 64 + 32768,    &Vsh[sel][w * 2048 + 1024]);\
    gload_lds16(Vg + (size_t)(jt) * 64 + 49152,    &Vsh[sel][w * 2048 + 1536]);\
  }

  // Q fragments (held in registers for the whole block)
  const u16* Qp = Q + hb + (size_t)(qb + l31) * 64 + hi * 8;
  const bf16x8 qf0 = *(const bf16x8*)(Qp);
  const bf16x8 qf1 = *(const bf16x8*)(Qp + 16);
  const bf16x8 qf2 = *(const bf16x8*)(Qp + 32);
  const bf16x8 qf3 = *(const bf16x8*)(Qp + 48);

  f32x16 o0 = (f32x16)0.0f, o1 = (f32x16)0.0f;
  float mrun = -1e30f, lrun = 0.0f;

  const int xr = l31 & 7;  // read-side swizzle key

  STAGEA(0, 0)
  if (T > 1) {
    STAGEA(1, 1)
    asm volatile("s_waitcnt vmcnt(8)" ::: "memory");
  } else {
    asm volatile("s_waitcnt vmcnt(0)" ::: "memory");
  }
  __builtin_amdgcn_sched_barrier(0);
  __builtin_amdgcn_s_barrier();
  __builtin_amdgcn_sched_barrier(0);

  int cur = 0;
  for (int jt = 0; jt < T; ++jt) {
    const bool pf = (jt + 2 < T);
    int nb = cur + 2; if (nb >= 3) nb -= 3;
    if (pf) STAGEA(nb, jt + 2)
    const u16* Kb = Ksh[cur];
    const u16* Vb = Vsh[cur];
    // K fragments: row = s*32+l31, want slot 2c+hi -> read slot ^ (row&7)
    bf16x8 kf[2][4];
#pragma unroll
    for (int s = 0; s < 2; ++s)
#pragma unroll
      for (int c = 0; c < 4; ++c)
        kf[s][c] = *(const bf16x8*)&Kb[(s * 32 + l31) * 64 + (((2 * c + hi) ^ xr) * 8)];

    // S^T[kpos][q] = K . Q^T
    f32x16 s0 = (f32x16)0.0f, s1 = (f32x16)0.0f;
    __builtin_amdgcn_s_setprio(1);
    s0 = __builtin_amdgcn_mfma_f32_32x32x16_bf16(kf[0][0], qf0, s0, 0, 0, 0);
    s1 = __builtin_amdgcn_mfma_f32_32x32x16_bf16(kf[1][0], qf0, s1, 0, 0, 0);
    s0 = __builtin_amdgcn_mfma_f32_32x32x16_bf16(kf[0][1], qf1, s0, 0, 0, 0);
    s1 = __builtin_amdgcn_mfma_f32_32x32x16_bf16(kf[1][1], qf1, s1, 0, 0, 0);
    s0 = __builtin_amdgcn_mfma_f32_32x32x16_bf16(kf[0][2], qf2, s0, 0, 0, 0);
    s1 = __builtin_amdgcn_mfma_f32_32x32x16_bf16(kf[1][2], qf2, s1, 0, 0, 0);
    s0 = __builtin_amdgcn_mfma_f32_32x32x16_bf16(kf[0][3], qf3, s0, 0, 0, 0);
    s1 = __builtin_amdgcn_mfma_f32_32x32x16_bf16(kf[1][3], qf3, s1, 0, 0, 0);
    __builtin_amdgcn_s_setprio(0);

    // causal mask (diagonal tile only; qrel = w*32 + l31)
    if (jt == T - 1) {
      const int qrel = w * 32 + l31;
      const int h4 = hi * 4;
#pragma unroll
      for (int r = 0; r < 16; ++r) {
        const int kp = (r & 3) + ((r >> 2) << 3) + h4;
        s0[r] = (kp <= qrel) ? s0[r] : -1e30f;
        s1[r] = (kp + 32 <= qrel) ? s1[r] : -1e30f;
      }
    }

    // ---- in-register online softmax (lane pair (l31,hi) = one q-row) ----
    float t8[8];
#pragma unroll
    for (int r = 0; r < 8; ++r)
      t8[r] = fmaxf(fmaxf(s0[r], s0[r + 8]), fmaxf(s1[r], s1[r + 8]));
    float tm = fmaxf(fmaxf(fmaxf(t8[0], t8[1]), fmaxf(t8[2], t8[3])),
                     fmaxf(fmaxf(t8[4], t8[5]), fmaxf(t8[6], t8[7])));
    tm = fmaxf(tm, __shfl_xor(tm, 32));
    if (!__all(tm <= mrun)) {
      const float mnew = fmaxf(mrun, tm);
      const float al = fast_exp2((mrun - mnew) * SC);
      mrun = mnew;
      lrun *= al;
#pragma unroll
      for (int r = 0; r < 16; ++r) { o0[r] *= al; o1[r] *= al; }
    }
    const float nb2 = -mrun * SC;
#pragma unroll
    for (int r = 0; r < 16; ++r) {
      s0[r] = fast_exp2(fmaf(s0[r], SC, nb2));
      s1[r] = fast_exp2(fmaf(s1[r], SC, nb2));
    }
    float u8[8];
#pragma unroll
    for (int r = 0; r < 8; ++r)
      u8[r] = (s0[r] + s0[r + 8]) + (s1[r] + s1[r + 8]);
    lrun += ((u8[0] + u8[1]) + (u8[2] + u8[3])) + ((u8[4] + u8[5]) + (u8[6] + u8[7]));

    // ---- pack P to bf16 B-fragments (cvt_pk + permlane32_swap, T12) ----
    bf16x8 pb0, pb1, pb2, pb3;
#define PACK_CHUNK(sv, bb, dst)                                   \
    {                                                             \
      u32 a0 = cvtpk(sv[bb + 0], sv[bb + 1]);                     \
      u32 a1 = cvtpk(sv[bb + 2], sv[bb + 3]);                     \
      u32 a2 = cvtpk(sv[bb + 4], sv[bb + 5]);                     \
      u32 a3 = cvtpk(sv[bb + 6], sv[bb + 7]);                     \
      plswap(a0, a2);                                             \
      plswap(a1, a3);                                             \
      u32x4 fv = {a0, a1, a2, a3};                                \
      dst = __builtin_bit_cast(bf16x8, fv);                       \
    }
    PACK_CHUNK(s0, 0, pb0)
    PACK_CHUNK(s0, 8, pb1)
    PACK_CHUNK(s1, 0, pb2)
    PACK_CHUNK(s1, 8, pb3)
#undef PACK_CHUNK

    // V^T fragments: row = mt*32+l31 (d), want slot 2c+hi -> read slot ^ (row&7)
    bf16x8 vf[2][4];
#pragma unroll
    for (int mt = 0; mt < 2; ++mt)
#pragma unroll
      for (int c = 0; c < 4; ++c)
        vf[mt][c] = *(const bf16x8*)&Vb[(mt * 32 + l31) * 64 + (((2 * c + hi) ^ xr) * 8)];

    // ---- O^T[d][q] += V^T . P^T ----
    __builtin_amdgcn_s_setprio(1);
    o0 = __builtin_amdgcn_mfma_f32_32x32x16_bf16(vf[0][0], pb0, o0, 0, 0, 0);
    o1 = __builtin_amdgcn_mfma_f32_32x32x16_bf16(vf[1][0], pb0, o1, 0, 0, 0);
    o0 = __builtin_amdgcn_mfma_f32_32x32x16_bf16(vf[0][1], pb1, o0, 0, 0, 0);
    o1 = __builtin_amdgcn_mfma_f32_32x32x16_bf16(vf[1][1], pb1, o1, 0, 0, 0);
    o0 = __builtin_amdgcn_mfma_f32_32x32x16_bf16(vf[0][2], pb2, o0, 0, 0, 0);
    o1 = __builtin_amdgcn_mfma_f32_32x32x16_bf16(vf[1][2], pb2, o1, 0, 0, 0);
    o0 = __builtin_amdgcn_mfma_f32_32x32x16_bf16(vf[0][3], pb3, o0, 0, 0, 0);
    o1 = __builtin_amdgcn_mfma_f32_32x32x16_bf16(vf[1][3], pb3, o1, 0, 0, 0);
    __builtin_amdgcn_s_setprio(0);

    // counted wait: keep the 8 loads for tile jt+2 in flight across the barrier
    if (pf) asm volatile("s_waitcnt vmcnt(8)" ::: "memory");
    else    asm volatile("s_waitcnt vmcnt(0)" ::: "memory");
    __builtin_amdgcn_sched_barrier(0);
    __builtin_amdgcn_s_barrier();
    __builtin_amdgcn_sched_barrier(0);
    cur = (cur + 1 == 3) ? 0 : cur + 1;
  }
#undef STAGEA

  // ---- epilogue: combine partner row-sums, normalize, store bf16 (per wave) ----
  const float lt = lrun + __shfl_xor(lrun, 32);
  const float inv = 1.0f / lt;
  u16* aorow = AO + (size_t)(b * 2048 + qb + l31) * 1024 + h * 64 + hi * 4;
#pragma unroll
  for (int g2 = 0; g2 < 4; ++g2) {
    u32 w0 = cvtpk(o0[4 * g2 + 0] * inv, o0[4 * g2 + 1] * inv);
    u32 w1 = cvtpk(o0[4 * g2 + 2] * inv, o0[4 * g2 + 3] * inv);
    u32x2 ww = {w0, w1};
    *(u32x2*)(aorow + g2 * 8) = ww;
  }
#pragma unroll
  for (int g2 = 0; g2 < 4; ++g2) {
    u32 w0 = cvtpk(o1[4 * g2 + 0] * inv, o1[4 * g2 + 1] * inv);
    u32 w1 = cvtpk(o1[4 * g2 + 2] * inv, o1[4 * g2 + 3] * inv);
    u32x2 ww = {w0, w1};
    *(u32x2*)(aorow + 32 + g2 * 8) = ww;
  }
}

extern "C" void kernel_launch(void* const* d_in, const int* in_sizes, int n_in,
                              void* d_out, int out_size, void* d_ws, size_t ws_size,
                              hipStream_t stream) {
  const float* x      = (const float*)d_in[0];
  const float* w_attn = (const float*)d_in[1];
  const float* b_attn = (const float*)d_in[2];
  const float* w_proj = (const float*)d_in[3];
  const float* b_proj = (const float*)d_in[4];
  float* out = (float*)d_out;

  char* ws = (char*)d_ws;
  u16* x_bf  = (u16*)(ws);                    // [4096][1024] bf16 (8 MB); dead after gemm0
  u16* wat_t = (u16*)(ws + 8388608);          // [3072][1024] bf16   (6 MB)
  u16* wpj_t = (u16*)(ws + 14680064);         // [1024][1024] bf16   (2 MB)
  u16* q_ws  = (u16*)(ws + 16777216);         // [B,H,S,d] bf16      (8 MB)
  u16* k_ws  = (u16*)(ws + 25165824);         // [B,H,S,d] bf16      (8 MB)
  u16* v_ws  = (u16*)(ws + 33554432);         // [B,H,S,d] bf16      (8 MB)
  u16* a_ws  = (u16*)(ws + 41943040);         // [B,S,nx]  bf16      (8 MB)
  u16* vT_ws = (u16*)(ws);                    // [B,H,d,S] bf16, reuses x_bf region

  k_cvt<<<4096, 256, 0, stream>>>(x, x_bf, 4194304);
  k_tcvt<<<dim3(96, 32), dim3(32, 8), 0, stream>>>(w_attn, wat_t, 1024, 3072);
  k_tcvt<<<dim3(32, 32), dim3(32, 8), 0, stream>>>(w_proj, wpj_t, 1024, 1024);

  k_gemm<0><<<dim3(24, 32), 256, 0, stream>>>(x_bf, wat_t, b_attn,
                                              q_ws, k_ws, v_ws,
                                              out + 4194304, out + 8388608, nullptr);

  k_vt<<<dim3(32, 32), 256, 0, stream>>>(v_ws, vT_ws);

  k_attn<<<dim3(1024), 128, 0, stream>>>(q_ws, k_ws, vT_ws, a_ws);

  k_gemm<1><<<dim3(8, 32), 256, 0, stream>>>(a_ws, wpj_t, b_proj,
                                             nullptr, nullptr, nullptr,
                                             nullptr, nullptr, out);
}